// Round 1
// baseline (674.322 us; speedup 1.0000x reference)
//
#include <hip/hip_runtime.h>
#include <hip/hip_bf16.h>
#include <stdint.h>

// ---------------- problem constants ----------------
#define NH     16
#define QRANK  1536
#define NOPE_  128
#define QKHD   192
#define B_     2
#define S_     2048
#define MAXSEQ 2048
#define EPS_   1e-6f
#define SCALE_ 0.07216878364870322f  // 192^-0.5

typedef __attribute__((ext_vector_type(4))) float f32x4;
typedef __attribute__((ext_vector_type(8))) short short8;
typedef __attribute__((ext_vector_type(4))) short short4v;

__device__ inline short f2bf(float f){
  uint32_t u = __builtin_bit_cast(uint32_t, f);
  uint32_t r = (u + 0x7FFFu + ((u >> 16) & 1u)) >> 16;
  return (short)(uint16_t)r;
}
__device__ inline float bf2f(short s){
  uint32_t u = ((uint32_t)(uint16_t)s) << 16;
  return __builtin_bit_cast(float, u);
}

// ---------------- f32 -> bf16 convert (vectorized) ----------------
__global__ void k_f2b(const float* __restrict__ in, short* __restrict__ out, long n){
  long i = ((long)blockIdx.x * blockDim.x + threadIdx.x) * 4;
  long stride = (long)gridDim.x * blockDim.x * 4;
  for(; i < n; i += stride){
    float4 v = *reinterpret_cast<const float4*>(in + i);
    short4v o;
    o.x = f2bf(v.x); o.y = f2bf(v.y); o.z = f2bf(v.z); o.w = f2bf(v.w);
    *reinterpret_cast<short4v*>(out + i) = o;
  }
}

// ---------------- GEMM: C[M][N] = A[M][K] @ B[N][K]^T + bias ----------------
// A,B bf16 row-major. BM=128 fixed, BN template (128 or 64). 4 waves 2x2.
template<int BN, bool OUT_BF16>
__global__ __launch_bounds__(256)
void k_gemm_bt(const short* __restrict__ A, const short* __restrict__ Bm,
               const float* __restrict__ bias, float biasScale,
               void* __restrict__ Cp, int M, int N, int K, int ldc)
{
  constexpr int BM = 128, PAD = 40;
  constexpr int WN = BN / 2, FN = WN / 16;
  __shared__ short As[BM * PAD];
  __shared__ short Bs[BN * PAD];
  const int tid = threadIdx.x;
  const int l = tid & 63, wid = tid >> 6;
  const int wr = wid >> 1, wc = wid & 1;
  const long m0 = (long)blockIdx.x * BM;
  const long n0 = (long)blockIdx.y * BN;
  const int lrow = l & 15, lk = (l >> 4) * 8;

  f32x4 acc[4][FN];
  for(int m = 0; m < 4; m++) for(int n = 0; n < FN; n++) acc[m][n] = (f32x4)0.0f;

  for(int kt = 0; kt < K; kt += 32){
    #pragma unroll
    for(int i = 0; i < BM/64; i++){
      int c = tid + 256*i;
      int row = c >> 2, ko = (c & 3) * 8;
      short8 v = *reinterpret_cast<const short8*>(&A[(m0 + row)*(long)K + kt + ko]);
      *reinterpret_cast<short8*>(&As[row*PAD + ko]) = v;
    }
    #pragma unroll
    for(int i = 0; i < BN/64; i++){
      int c = tid + 256*i;
      int row = c >> 2, ko = (c & 3) * 8;
      short8 v = *reinterpret_cast<const short8*>(&Bm[(n0 + row)*(long)K + kt + ko]);
      *reinterpret_cast<short8*>(&Bs[row*PAD + ko]) = v;
    }
    __syncthreads();
    short8 af[4], bfv[FN];
    #pragma unroll
    for(int m = 0; m < 4; m++)
      af[m] = *reinterpret_cast<const short8*>(&As[(wr*64 + m*16 + lrow)*PAD + lk]);
    #pragma unroll
    for(int n = 0; n < FN; n++)
      bfv[n] = *reinterpret_cast<const short8*>(&Bs[(wc*WN + n*16 + lrow)*PAD + lk]);
    #pragma unroll
    for(int m = 0; m < 4; m++)
      #pragma unroll
      for(int n = 0; n < FN; n++)
        acc[m][n] = __builtin_amdgcn_mfma_f32_16x16x32_bf16(af[m], bfv[n], acc[m][n], 0, 0, 0);
    __syncthreads();
  }
  #pragma unroll
  for(int m = 0; m < 4; m++){
    int row_l = wr*64 + m*16 + (l >> 4)*4;
    #pragma unroll
    for(int n = 0; n < FN; n++){
      int col = (int)n0 + wc*WN + n*16 + (l & 15);
      float bv = bias ? bias[col]*biasScale : 0.0f;
      #pragma unroll
      for(int r = 0; r < 4; r++){
        long row = m0 + row_l + r;
        float v = acc[m][n][r] + bv;
        if constexpr (OUT_BF16) ((short*)Cp)[row*(long)ldc + col] = f2bf(v);
        else                    ((float*)Cp)[row*(long)ldc + col] = v;
      }
    }
  }
}

// ---------------- RMS norm over 1536, rows=4096, bf16 out ----------------
__global__ __launch_bounds__(256)
void k_rms_q(const float* __restrict__ in, const float* __restrict__ w,
             short* __restrict__ out)
{
  const int row = blockIdx.x;
  const int tid = threadIdx.x;
  const float* p = in + (long)row * QRANK;
  float v[6]; float ss = 0.0f;
  #pragma unroll
  for(int i = 0; i < 6; i++){ v[i] = p[tid + 256*i]; ss += v[i]*v[i]; }
  #pragma unroll
  for(int off = 1; off < 64; off <<= 1) ss += __shfl_xor(ss, off);
  __shared__ float red[4];
  if((tid & 63) == 0) red[tid >> 6] = ss;
  __syncthreads();
  ss = red[0] + red[1] + red[2] + red[3];
  float scale = rsqrtf(ss / (float)QRANK + EPS_);
  #pragma unroll
  for(int i = 0; i < 6; i++){
    int c = tid + 256*i;
    out[(long)row*QRANK + c] = f2bf(v[i] * scale * w[c]);
  }
}

// ---------------- q assemble: split nope / rope the pe part ----------------
// q bf16 (B*S, 3072) -> qn (B*S*16,128) bf16, qfull[...,128:192] roped bf16
__global__ __launch_bounds__(256)
void k_qassemble(const short* __restrict__ q, const float* __restrict__ freqs,
                 short* __restrict__ qn, short* __restrict__ qfull)
{
  int wid = threadIdx.x >> 6, l = threadIdx.x & 63;
  long hr = (long)blockIdx.x*4 + wid;      // head-row 0..65535
  long bs = hr >> 4; int h = (int)(hr & 15);
  int s = (int)(bs & (S_ - 1));
  const short* src = q + bs*3072 + h*QKHD;
  qn[hr*128 + l]      = src[l];
  qn[hr*128 + 64 + l] = src[64 + l];
  float v = bf2f(src[128 + l]);
  int i = l >> 1;
  float cs = freqs[(s*32 + i)*2], sn = freqs[(s*32 + i)*2 + 1];
  float pv = __shfl_xor(v, 1);
  float r = (l & 1) ? (pv*sn + v*cs) : (v*cs - pv*sn);
  qfull[hr*QKHD + 128 + l] = f2bf(r);
}

// ---------------- kv: RMS(192) + rope(last 64) + cache merge ----------------
__global__ __launch_bounds__(256)
void k_kvproc(const float* __restrict__ kvf, const float* __restrict__ w,
              const float* __restrict__ freqs, const float* __restrict__ cache,
              const int* __restrict__ sp_ptr, short* __restrict__ kf)
{
  int wid = threadIdx.x >> 6, l = threadIdx.x & 63;
  long row = (long)blockIdx.x*4 + wid;     // 0 .. B*MAXSEQ-1
  int b = (int)(row >> 11);
  int t = (int)(row & (MAXSEQ - 1));
  int sp = sp_ptr[0];
  int end = sp + S_;
  if(t < sp){
    const float* c = cache + row*QKHD;
    kf[row*QKHD + l]       = f2bf(c[l]);
    kf[row*QKHD + 64 + l]  = f2bf(c[64 + l]);
    kf[row*QKHD + 128 + l] = f2bf(c[128 + l]);
    return;
  }
  if(t >= end) return;
  int s = t - sp;
  const float* p = kvf + ((long)b*S_ + s)*QKHD;
  float v0 = p[l], v1 = p[64 + l], v2 = p[128 + l];
  float ss = v0*v0 + v1*v1 + v2*v2;
  #pragma unroll
  for(int off = 1; off < 64; off <<= 1) ss += __shfl_xor(ss, off);
  float scale = rsqrtf(ss / (float)QKHD + EPS_);
  float n0 = v0*scale*w[l], n1 = v1*scale*w[64 + l], n2 = v2*scale*w[128 + l];
  kf[row*QKHD + l]      = f2bf(n0);
  kf[row*QKHD + 64 + l] = f2bf(n1);
  int i = l >> 1;
  float cs = freqs[(s*32 + i)*2], sn = freqs[(s*32 + i)*2 + 1];
  float pv = __shfl_xor(n2, 1);
  float r = (l & 1) ? (pv*sn + n2*cs) : (n2*cs - pv*sn);
  kf[row*QKHD + 128 + l] = f2bf(r);
}

// ---------------- flash attention ----------------
// grid (S/128, NH, B), block 256 (4 waves x 32 q-rows). t-tiles of 32.
__global__ __launch_bounds__(256)
void k_attn(const short* __restrict__ qfull, const short* __restrict__ kf,
            const int* __restrict__ sp_ptr, short* __restrict__ oh)
{
  constexpr int PK = 200, PVD = 40, PP = 40;
  __shared__ short Ks[32 * PK];        // [t][k 0..191] padded
  __shared__ short Vt[128 * PVD];      // [d][t] transposed V
  __shared__ short Ps[4][32 * PP];     // per-wave P tile [q][t]
  const int tid = threadIdx.x;
  const int l = tid & 63, wq = tid >> 6;
  const int lrow = l & 15, lhi = l >> 4;
  const int q0 = blockIdx.x * 128;
  const int h = blockIdx.y;
  const int b = blockIdx.z;
  const int sp = sp_ptr[0];

  // hoist Q fragments (rows q0+wq*32 .. +31, full 192-k)
  short8 qa[2][6];
  #pragma unroll
  for(int qf = 0; qf < 2; qf++){
    int s = q0 + wq*32 + qf*16 + lrow;
    const short* qp = qfull + (((long)b*S_ + s)*NH + h)*QKHD + lhi*8;
    #pragma unroll
    for(int ks = 0; ks < 6; ks++) qa[qf][ks] = *reinterpret_cast<const short8*>(qp + ks*32);
  }
  f32x4 o[2][8];
  for(int qf = 0; qf < 2; qf++) for(int df = 0; df < 8; df++) o[qf][df] = (f32x4)0.0f;
  float mrun[8], lrun[8];
  #pragma unroll
  for(int i = 0; i < 8; i++){ mrun[i] = -1e30f; lrun[i] = 0.0f; }

  const int hi = q0 + 128 + sp;       // exclusive bound on t for this block
  const int nt = (hi + 31) >> 5;

  for(int t0 = 0; t0 < nt; t0++){
    const int T0 = t0 * 32;
    // stage K tile [32][192]
    #pragma unroll
    for(int i = 0; i < 3; i++){
      int c = tid + 256*i;                       // 0..767
      int trow = c / 24, ko = (c % 24) * 8;
      short8 v = *reinterpret_cast<const short8*>(&kf[((long)b*MAXSEQ + T0 + trow)*QKHD + ko]);
      *reinterpret_cast<short8*>(&Ks[trow*PK + ko]) = v;
    }
    // stage V^T tile [128][32]
    #pragma unroll
    for(int i = 0; i < 8; i++){
      int c = tid + 256*i;                       // 0..2047
      int trow = c >> 6, dp = c & 63;
      const short* src = &kf[((long)b*MAXSEQ + T0 + trow)*QKHD + dp*2];
      short x0 = src[0], x1 = src[1];
      Vt[(dp*2)*PVD + trow]     = x0;
      Vt[(dp*2 + 1)*PVD + trow] = x1;
    }
    __syncthreads();
    // scores: S = Q @ K^T   (32q x 32t per wave)
    f32x4 sc[2][2];
    for(int qf = 0; qf < 2; qf++) for(int tf = 0; tf < 2; tf++) sc[qf][tf] = (f32x4)0.0f;
    #pragma unroll
    for(int ks = 0; ks < 6; ks++){
      #pragma unroll
      for(int tf = 0; tf < 2; tf++){
        short8 bfr = *reinterpret_cast<const short8*>(&Ks[(tf*16 + lrow)*PK + ks*32 + lhi*8]);
        #pragma unroll
        for(int qf = 0; qf < 2; qf++)
          sc[qf][tf] = __builtin_amdgcn_mfma_f32_16x16x32_bf16(qa[qf][ks], bfr, sc[qf][tf], 0, 0, 0);
      }
    }
    // online softmax update
    #pragma unroll
    for(int qf = 0; qf < 2; qf++){
      #pragma unroll
      for(int r = 0; r < 4; r++){
        int q = q0 + wq*32 + qf*16 + lhi*4 + r;
        float s0 = sc[qf][0][r] * SCALE_;
        float s1 = sc[qf][1][r] * SCALE_;
        int tcol = T0 + lrow;
        if(tcol > q + sp)      s0 = -1e30f;
        if(tcol + 16 > q + sp) s1 = -1e30f;
        float mx = fmaxf(s0, s1);
        #pragma unroll
        for(int off = 1; off < 16; off <<= 1) mx = fmaxf(mx, __shfl_xor(mx, off));
        int ri = qf*4 + r;
        float mnew = fmaxf(mrun[ri], mx);
        float corr = __expf(mrun[ri] - mnew);
        float p0 = __expf(s0 - mnew);
        float p1 = __expf(s1 - mnew);
        float psum = p0 + p1;
        #pragma unroll
        for(int off = 1; off < 16; off <<= 1) psum += __shfl_xor(psum, off);
        lrun[ri] = lrun[ri]*corr + psum;
        mrun[ri] = mnew;
        #pragma unroll
        for(int df = 0; df < 8; df++) o[qf][df][r] *= corr;
        int prow = qf*16 + lhi*4 + r;
        Ps[wq][prow*PP + lrow]      = f2bf(p0);
        Ps[wq][prow*PP + 16 + lrow] = f2bf(p1);
      }
    }
    // PV: O += P @ V  (A-frag from Ps, B-frag from Vt; k = 32 in one mfma)
    #pragma unroll
    for(int df = 0; df < 8; df++){
      short8 vfr = *reinterpret_cast<const short8*>(&Vt[(df*16 + lrow)*PVD + lhi*8]);
      #pragma unroll
      for(int qf = 0; qf < 2; qf++){
        short8 pfr = *reinterpret_cast<const short8*>(&Ps[wq][(qf*16 + lrow)*PP + lhi*8]);
        o[qf][df] = __builtin_amdgcn_mfma_f32_16x16x32_bf16(pfr, vfr, o[qf][df], 0, 0, 0);
      }
    }
    __syncthreads();
  }
  // epilogue: normalize + store per-head output bf16
  #pragma unroll
  for(int qf = 0; qf < 2; qf++){
    #pragma unroll
    for(int r = 0; r < 4; r++){
      int s = q0 + wq*32 + qf*16 + lhi*4 + r;
      float inv = 1.0f / lrun[qf*4 + r];
      #pragma unroll
      for(int df = 0; df < 8; df++)
        oh[(((long)b*S_ + s)*NH + h)*128 + df*16 + lrow] = f2bf(o[qf][df][r] * inv);
    }
  }
}

// ---------------- head-sum: (B*S,16,128) -> (B*S,128) ----------------
__global__ void k_redheads(const short* __restrict__ ohp, short* __restrict__ hs){
  long row = blockIdx.x;
  int d = threadIdx.x;
  float acc = 0.0f;
  #pragma unroll
  for(int h = 0; h < NH; h++) acc += bf2f(ohp[(row*NH + h)*128 + d]);
  hs[row*128 + d] = f2bf(acc);
}

// ---------------- ws layout (bytes) — total 119,308,288 ----------------
static constexpr size_t OFF_X16   = 0;          // bf16 x           16,777,216
static constexpr size_t OFF_WQA   = 16777216;   // bf16 wqa          6,291,456
static constexpr size_t OFF_WQB   = 23068672;   // bf16 wqb          9,437,184
static constexpr size_t OFF_WKV   = 32505856;   // bf16 wkva           786,432
static constexpr size_t OFF_WUK   = 33292288;   // bf16 wuk             32,768
static constexpr size_t OFF_WUV   = 33325056;   // bf16 wuv            524,288
static constexpr size_t OFF_QNORM = 33849344;   // bf16 qnorm       12,582,912
static constexpr size_t OFF_QFULL = 46432256;   // bf16 qfull       25,165,824
static constexpr size_t OFF_KFULL = 71598080;   // bf16 k cache      1,572,864
static constexpr size_t OFF_HSUM  = 73170944;   // bf16 head sum     1,048,576
static constexpr size_t OFF_SCR   = 74219520;   // overlay region   45,088,768
static constexpr size_t OFF_QA    = OFF_SCR;              // f32 qa (phase 1)
static constexpr size_t OFF_Q16   = OFF_SCR;              // bf16 q (phase 2, qa dead)
static constexpr size_t OFF_QN    = OFF_SCR + 25165824;   // bf16 q_nope
static constexpr size_t OFF_KVF   = OFF_SCR + 41943040;   // f32 kv
static constexpr size_t OFF_OH    = OFF_SCR;              // bf16 per-head O (phase 3)

extern "C" void kernel_launch(void* const* d_in, const int* in_sizes, int n_in,
                              void* d_out, int out_size, void* d_ws, size_t ws_size,
                              hipStream_t stream)
{
  const float* x      = (const float*)d_in[0];
  const int*   sp     = (const int*)  d_in[1];
  const float* freqs  = (const float*)d_in[2];
  const float* cache  = (const float*)d_in[4];
  const float* wqa_w  = (const float*)d_in[5];
  const float* wqa_b  = (const float*)d_in[6];
  const float* wqb_w  = (const float*)d_in[7];
  const float* wqb_b  = (const float*)d_in[8];
  const float* qnw    = (const float*)d_in[9];
  const float* wkva_w = (const float*)d_in[10];
  const float* wkva_b = (const float*)d_in[11];
  const float* knw    = (const float*)d_in[12];
  const float* wuk_w  = (const float*)d_in[13];
  const float* wuk_b  = (const float*)d_in[14];
  const float* wuv_w  = (const float*)d_in[15];
  const float* wuv_b  = (const float*)d_in[16];

  char* ws = (char*)d_ws;
  short* X16   = (short*)(ws + OFF_X16);
  short* WQA16 = (short*)(ws + OFF_WQA);
  short* WQB16 = (short*)(ws + OFF_WQB);
  short* WKV16 = (short*)(ws + OFF_WKV);
  short* WUK16 = (short*)(ws + OFF_WUK);
  short* WUV16 = (short*)(ws + OFF_WUV);
  short* QNORM = (short*)(ws + OFF_QNORM);
  short* QFULL = (short*)(ws + OFF_QFULL);
  short* KFULL = (short*)(ws + OFF_KFULL);
  short* HSUM  = (short*)(ws + OFF_HSUM);
  float* QA    = (float*)(ws + OFF_QA);
  short* Q16   = (short*)(ws + OFF_Q16);
  short* QN16  = (short*)(ws + OFF_QN);
  float* KVF   = (float*)(ws + OFF_KVF);
  short* OH16  = (short*)(ws + OFF_OH);

  auto cvt = [&](const float* src, short* dst, long n){
    long blocks = (n/4 + 255) / 256; if(blocks > 2048) blocks = 2048;
    k_f2b<<<(int)blocks, 256, 0, stream>>>(src, dst, n);
  };
  cvt(x,      X16,   (long)B_*S_*2048);
  cvt(wqa_w,  WQA16, (long)QRANK*2048);
  cvt(wqb_w,  WQB16, (long)NH*QKHD*QRANK);
  cvt(wkva_w, WKV16, (long)QKHD*2048);
  cvt(wuk_w,  WUK16, (long)NOPE_*NOPE_);
  cvt(wuv_w,  WUV16, (long)2048*NOPE_);

  // qa = x @ wqa^T + b   (f32)
  k_gemm_bt<128,false><<<dim3(32,12), 256, 0, stream>>>(X16, WQA16, wqa_b, 1.0f, QA, 4096, QRANK, 2048, QRANK);
  // rms norm -> bf16
  k_rms_q<<<4096, 256, 0, stream>>>(QA, qnw, QNORM);
  // q = qnorm @ wqb^T + b   (bf16)
  k_gemm_bt<128,true><<<dim3(32,24), 256, 0, stream>>>(QNORM, WQB16, wqb_b, 1.0f, Q16, 4096, NH*QKHD, QRANK, NH*QKHD);
  // split nope / rope pe
  k_qassemble<<<16384, 256, 0, stream>>>(Q16, freqs, QN16, QFULL);
  // q_abs = q_nope @ wuk^T + b  -> qfull[...,:128]
  k_gemm_bt<128,true><<<dim3(512,1), 256, 0, stream>>>(QN16, WUK16, wuk_b, 1.0f, QFULL, 65536, 128, 128, QKHD);
  // kv = x @ wkva^T + b  (f32)
  k_gemm_bt<64,false><<<dim3(32,3), 256, 0, stream>>>(X16, WKV16, wkva_b, 1.0f, KVF, 4096, QKHD, 2048, QKHD);
  // rms + rope + cache merge -> k_full bf16
  k_kvproc<<<1024, 256, 0, stream>>>(KVF, knw, freqs, cache, sp, KFULL);
  // flash attention -> per-head O bf16
  k_attn<<<dim3(16,16,2), 256, 0, stream>>>(QFULL, KFULL, sp, OH16);
  // head sum
  k_redheads<<<4096, 128, 0, stream>>>(OH16, HSUM);
  // out = hsum @ wuv^T + 16*b  (f32 -> d_out)
  k_gemm_bt<128,false><<<dim3(32,16), 256, 0, stream>>>(HSUM, WUV16, wuv_b, 16.0f, (float*)d_out, 4096, 2048, NOPE_, 2048);
}